// Round 1
// baseline (1703.732 us; speedup 1.0000x reference)
//
#include <hip/hip_runtime.h>

#define EDIM 10
#define TDIM 50
#define BATCH 65536
// collapsed-weight layout per gate (stride 224 floats):
//   [0..99]   A = Wi@Ws   (indexed [k*10+e])
//   [100..199] Bm = Wh@Ws
//   [200..209] c = bi@Ws + bs
// gates: 0=r, 1=z, 2=h-candidate
#define GSTRIDE 224

__device__ __forceinline__ float fast_sigmoid(float x) {
    float e = __expf(-x);
    return __builtin_amdgcn_rcpf(1.0f + e);
}
__device__ __forceinline__ float fast_tanh(float x) {
    // 1 - 2/(exp(2x)+1); safe at +-inf
    float e = __expf(2.0f * x);
    return 1.0f - 2.0f * __builtin_amdgcn_rcpf(e + 1.0f);
}

__global__ void augru_setup(
    const float* __restrict__ Wi_r, const float* __restrict__ bi_r,
    const float* __restrict__ Wh_r, const float* __restrict__ Ws_r, const float* __restrict__ bs_r,
    const float* __restrict__ Wi_z, const float* __restrict__ bi_z,
    const float* __restrict__ Wh_z, const float* __restrict__ Ws_z, const float* __restrict__ bs_z,
    const float* __restrict__ Wi_h, const float* __restrict__ bi_h,
    const float* __restrict__ Wh_h, const float* __restrict__ Wt_h, const float* __restrict__ bt_h,
    float* __restrict__ w)
{
    const float* Wi[3] = {Wi_r, Wi_z, Wi_h};
    const float* Wh[3] = {Wh_r, Wh_z, Wh_h};
    const float* Ws[3] = {Ws_r, Ws_z, Wt_h};
    const float* bi[3] = {bi_r, bi_z, bi_h};
    const float* bs[3] = {bs_r, bs_z, bt_h};
    for (int s = threadIdx.x; s < 3 * GSTRIDE; s += blockDim.x) {
        int g = s / GSTRIDE, rem = s % GSTRIDE;
        float v = 0.0f;
        if (rem < 100) {
            int i = rem / 10, e = rem % 10;
            #pragma unroll
            for (int j = 0; j < 10; j++) v += Wi[g][i * 10 + j] * Ws[g][j * 10 + e];
        } else if (rem < 200) {
            int i = (rem - 100) / 10, e = (rem - 100) % 10;
            #pragma unroll
            for (int j = 0; j < 10; j++) v += Wh[g][i * 10 + j] * Ws[g][j * 10 + e];
        } else if (rem < 210) {
            int e = rem - 200;
            v = bs[g][e];
            #pragma unroll
            for (int j = 0; j < 10; j++) v += bi[g][j] * Ws[g][j * 10 + e];
        }
        w[s] = v;
    }
}

__global__ __launch_bounds__(256) void augru_main(
    const float* __restrict__ x_all, const float* __restrict__ a_all,
    const float* __restrict__ h0, const float* __restrict__ w,
    float* __restrict__ out)
{
    const int b = blockIdx.x * 256 + threadIdx.x;
    const float2* xp = (const float2*)x_all + (size_t)b * (TDIM * EDIM / 2);
    const float2* ap = (const float2*)a_all + (size_t)b * (TDIM * EDIM / 2);

    float h[EDIM];
    #pragma unroll
    for (int e = 0; e < EDIM; e++) h[e] = h0[e];   // uniform -> s_load + broadcast

    float2 xc[5], ac[5];
    #pragma unroll
    for (int i = 0; i < 5; i++) { xc[i] = xp[i]; ac[i] = ap[i]; }

    const float* wp = w;
    #pragma unroll 1
    for (int t = 0; t < TDIM; t++) {
        // Make wp opaque each iteration: keeps weight loads inside the loop
        // (no 630-scalar LICM hoist) while keeping the address wave-uniform
        // so they select as s_load (SGPR operands are free in v_fmac).
        asm volatile("" : "+s"(wp));

        // prefetch next timestep's x/a (1-step lookahead hides VMEM latency)
        float2 xn[5], an[5];
        if (t < TDIM - 1) {
            #pragma unroll
            for (int i = 0; i < 5; i++) {
                xn[i] = xp[(t + 1) * 5 + i];
                an[i] = ap[(t + 1) * 5 + i];
            }
        }

        float x[EDIM], a[EDIM];
        #pragma unroll
        for (int i = 0; i < 5; i++) {
            x[2 * i] = xc[i].x; x[2 * i + 1] = xc[i].y;
            a[2 * i] = ac[i].x; a[2 * i + 1] = ac[i].y;
        }

        // ---- r and z gates: u = x@A + h@Bm + c ----
        float ur[EDIM], uz[EDIM];
        #pragma unroll
        for (int e = 0; e < EDIM; e++) {
            ur[e] = wp[0 * GSTRIDE + 200 + e];
            uz[e] = wp[1 * GSTRIDE + 200 + e];
        }
        #pragma unroll
        for (int k = 0; k < EDIM; k++) {
            float xk = x[k];
            #pragma unroll
            for (int e = 0; e < EDIM; e++) {
                ur[e] += xk * wp[0 * GSTRIDE + k * 10 + e];
                uz[e] += xk * wp[1 * GSTRIDE + k * 10 + e];
            }
        }
        #pragma unroll
        for (int k = 0; k < EDIM; k++) {
            float hk = h[k];
            #pragma unroll
            for (int e = 0; e < EDIM; e++) {
                ur[e] += hk * wp[0 * GSTRIDE + 100 + k * 10 + e];
                uz[e] += hk * wp[1 * GSTRIDE + 100 + k * 10 + e];
            }
        }
        float r[EDIM], z[EDIM];
        #pragma unroll
        for (int e = 0; e < EDIM; e++) {
            r[e] = fast_sigmoid(ur[e]);
            z[e] = fast_sigmoid(uz[e]);
        }

        // ---- candidate: uh = x@A_h + (h*z)@Bm_h + c_h ----
        float uh[EDIM];
        #pragma unroll
        for (int e = 0; e < EDIM; e++) uh[e] = wp[2 * GSTRIDE + 200 + e];
        #pragma unroll
        for (int k = 0; k < EDIM; k++) {
            float xk = x[k];
            #pragma unroll
            for (int e = 0; e < EDIM; e++) uh[e] += xk * wp[2 * GSTRIDE + k * 10 + e];
        }
        #pragma unroll
        for (int k = 0; k < EDIM; k++) {
            float gk = h[k] * z[k];
            #pragma unroll
            for (int e = 0; e < EDIM; e++) uh[e] += gk * wp[2 * GSTRIDE + 100 + k * 10 + e];
        }

        // ---- update: Ra = a*r; h = (1-Ra)*h + Ra*hc ----
        #pragma unroll
        for (int e = 0; e < EDIM; e++) {
            float hc = fast_tanh(uh[e]);
            float Ra = a[e] * r[e];
            h[e] = h[e] + Ra * (hc - h[e]);
        }

        if (t < TDIM - 1) {
            #pragma unroll
            for (int i = 0; i < 5; i++) { xc[i] = xn[i]; ac[i] = an[i]; }
        }
    }

    float2* op = (float2*)out + (size_t)b * (EDIM / 2);
    #pragma unroll
    for (int i = 0; i < 5; i++) op[i] = make_float2(h[2 * i], h[2 * i + 1]);
}

extern "C" void kernel_launch(void* const* d_in, const int* in_sizes, int n_in,
                              void* d_out, int out_size, void* d_ws, size_t ws_size,
                              hipStream_t stream) {
    const float* x  = (const float*)d_in[0];
    const float* a  = (const float*)d_in[1];
    const float* h0 = (const float*)d_in[2];
    float* w = (float*)d_ws;   // 672 floats of collapsed weights

    augru_setup<<<1, 256, 0, stream>>>(
        (const float*)d_in[3],  (const float*)d_in[4],  (const float*)d_in[5],
        (const float*)d_in[6],  (const float*)d_in[7],
        (const float*)d_in[8],  (const float*)d_in[9],  (const float*)d_in[10],
        (const float*)d_in[11], (const float*)d_in[12],
        (const float*)d_in[13], (const float*)d_in[14], (const float*)d_in[15],
        (const float*)d_in[16], (const float*)d_in[17],
        w);

    augru_main<<<BATCH / 256, 256, 0, stream>>>(x, a, h0, w, (float*)d_out);
}

// Round 3
// 1545.728 us; speedup vs baseline: 1.1022x; 1.1022x over previous
//
#include <hip/hip_runtime.h>

#define EDIM 10
#define TDIM 50
#define BATCH 65536
// collapsed-weight layout per gate (stride 224 floats = 56 float4):
//   floats [0..99]    A  = Wi@Ws   (indexed [k*10+e])
//   floats [100..199] Bm = Wh@Ws
//   floats [200..209] c  = bi@Ws + bs   (floats 210..223 zero pad)
// gates: 0=r, 1=z, 2=h-candidate
#define GSTRIDE 224
#define G4 56   // per-gate stride in float4 units

__device__ __forceinline__ float fast_sigmoid(float x) {
    float e = __expf(-x);
    return __builtin_amdgcn_rcpf(1.0f + e);
}
__device__ __forceinline__ float fast_tanh(float x) {
    float e = __expf(2.0f * x);
    return 1.0f - 2.0f * __builtin_amdgcn_rcpf(e + 1.0f);
}

// Accumulate u[e] += s[k] * M[k*10+e] over the 100-float matrix stored as 25
// float4s at Wb[0..25). All u/s indices are compile-time after unroll.
__device__ __forceinline__ void mat_acc(const float4* Wb, const float* s, float* u) {
    #pragma unroll
    for (int c = 0; c < 25; c++) {
        float4 wv = Wb[c];
        u[(4 * c + 0) % 10] = fmaf(s[(4 * c + 0) / 10], wv.x, u[(4 * c + 0) % 10]);
        u[(4 * c + 1) % 10] = fmaf(s[(4 * c + 1) / 10], wv.y, u[(4 * c + 1) % 10]);
        u[(4 * c + 2) % 10] = fmaf(s[(4 * c + 2) / 10], wv.z, u[(4 * c + 2) % 10]);
        u[(4 * c + 3) % 10] = fmaf(s[(4 * c + 3) / 10], wv.w, u[(4 * c + 3) % 10]);
    }
}

__device__ __forceinline__ void bias_init(const float4* Wb, float* u) {
    float4 b0 = Wb[0], b1 = Wb[1], b2 = Wb[2];
    u[0] = b0.x; u[1] = b0.y; u[2] = b0.z; u[3] = b0.w;
    u[4] = b1.x; u[5] = b1.y; u[6] = b1.z; u[7] = b1.w;
    u[8] = b2.x; u[9] = b2.y;
}

// Single fused kernel: per-block weight collapse into LDS (no workspace, no
// second kernel, no inter-kernel visibility dependence), then the recurrence.
// __launch_bounds__(256, 1): grid == 256 blocks == 1 block/CU regardless, so
// min-1-wave/EU is free and raises the VGPR cap 256 -> 512 (kills the spill
// that made rounds 1-2 run at 1.55 ms with 4.4 GB of scratch traffic).
__global__ __launch_bounds__(256, 1) void augru_main(
    const float* __restrict__ x_all, const float* __restrict__ a_all,
    const float* __restrict__ h0,
    const float* __restrict__ Wi_r, const float* __restrict__ bi_r,
    const float* __restrict__ Wh_r, const float* __restrict__ Ws_r, const float* __restrict__ bs_r,
    const float* __restrict__ Wi_z, const float* __restrict__ bi_z,
    const float* __restrict__ Wh_z, const float* __restrict__ Ws_z, const float* __restrict__ bs_z,
    const float* __restrict__ Wi_h, const float* __restrict__ bi_h,
    const float* __restrict__ Wh_h, const float* __restrict__ Wt_h, const float* __restrict__ bt_h,
    float* __restrict__ out)
{
    __shared__ __align__(16) float Wf[3 * GSTRIDE];   // 672 floats = 2.7 KB

    // ---- preamble: collapse (Wi@Ws, Wh@Ws, bi@Ws+bs) per gate into LDS ----
    for (int s = threadIdx.x; s < 3 * GSTRIDE; s += 256) {
        int g = s / GSTRIDE, rem = s % GSTRIDE;
        const float* Wi = (g == 0) ? Wi_r : (g == 1) ? Wi_z : Wi_h;
        const float* Wh = (g == 0) ? Wh_r : (g == 1) ? Wh_z : Wh_h;
        const float* Ws = (g == 0) ? Ws_r : (g == 1) ? Ws_z : Wt_h;
        const float* bi = (g == 0) ? bi_r : (g == 1) ? bi_z : bi_h;
        const float* bs = (g == 0) ? bs_r : (g == 1) ? bs_z : bt_h;
        float v = 0.0f;
        if (rem < 100) {
            int i = rem / 10, e = rem % 10;
            #pragma unroll
            for (int j = 0; j < 10; j++) v += Wi[i * 10 + j] * Ws[j * 10 + e];
        } else if (rem < 200) {
            int i = (rem - 100) / 10, e = (rem - 100) % 10;
            #pragma unroll
            for (int j = 0; j < 10; j++) v += Wh[i * 10 + j] * Ws[j * 10 + e];
        } else if (rem < 210) {
            int e = rem - 200;
            v = bs[e];
            #pragma unroll
            for (int j = 0; j < 10; j++) v += bi[j] * Ws[j * 10 + e];
        }
        Wf[s] = v;
    }
    __syncthreads();

    const int b = blockIdx.x * 256 + threadIdx.x;
    const float2* xp = (const float2*)x_all + (size_t)b * (TDIM * EDIM / 2);
    const float2* ap = (const float2*)a_all + (size_t)b * (TDIM * EDIM / 2);

    float h[EDIM];
    #pragma unroll
    for (int e = 0; e < EDIM; e++) h[e] = h0[e];

    float2 xc[5], ac[5];
    #pragma unroll
    for (int i = 0; i < 5; i++) { xc[i] = xp[i]; ac[i] = ap[i]; }

    int lz = 0;   // laundered zero: defeats LICM hoist of the (invariant) LDS
                  // weight reads out of the t-loop (hoisting 672 floats would
                  // blow past even the 512-VGPR budget and re-create the spill)
    #pragma unroll 1
    for (int t = 0; t < TDIM; t++) {
        asm volatile("" : "+v"(lz));
        const float4* WL = (const float4*)Wf + lz;   // addrspace(3) -> ds_read

        // prefetch next timestep's x/a (1-step lookahead hides VMEM latency)
        float2 xn[5], an[5];
        if (t < TDIM - 1) {
            #pragma unroll
            for (int i = 0; i < 5; i++) {
                xn[i] = xp[(t + 1) * 5 + i];
                an[i] = ap[(t + 1) * 5 + i];
            }
        }

        float x[EDIM], a[EDIM];
        #pragma unroll
        for (int i = 0; i < 5; i++) {
            x[2 * i] = xc[i].x; x[2 * i + 1] = xc[i].y;
            a[2 * i] = ac[i].x; a[2 * i + 1] = ac[i].y;
        }

        // ---- r and z gates: u = x@A + h@Bm + c ----
        float ur[EDIM], uz[EDIM];
        bias_init(WL + 0 * G4 + 50, ur);
        bias_init(WL + 1 * G4 + 50, uz);
        mat_acc(WL + 0 * G4 + 0,  x, ur);
        mat_acc(WL + 1 * G4 + 0,  x, uz);
        mat_acc(WL + 0 * G4 + 25, h, ur);
        mat_acc(WL + 1 * G4 + 25, h, uz);

        float r[EDIM], z[EDIM];
        #pragma unroll
        for (int e = 0; e < EDIM; e++) {
            r[e] = fast_sigmoid(ur[e]);
            z[e] = fast_sigmoid(uz[e]);
        }

        // ---- candidate: uh = x@A_h + (h*z)@Bm_h + c_h ----
        float uh[EDIM], hz[EDIM];
        #pragma unroll
        for (int k = 0; k < EDIM; k++) hz[k] = h[k] * z[k];
        bias_init(WL + 2 * G4 + 50, uh);
        mat_acc(WL + 2 * G4 + 0,  x, uh);
        mat_acc(WL + 2 * G4 + 25, hz, uh);

        // ---- update: Ra = a*r; h = (1-Ra)*h + Ra*hc ----
        #pragma unroll
        for (int e = 0; e < EDIM; e++) {
            float hc = fast_tanh(uh[e]);
            float Ra = a[e] * r[e];
            h[e] = h[e] + Ra * (hc - h[e]);
        }

        if (t < TDIM - 1) {
            #pragma unroll
            for (int i = 0; i < 5; i++) { xc[i] = xn[i]; ac[i] = an[i]; }
        }
    }

    float2* op = (float2*)out + (size_t)b * (EDIM / 2);
    #pragma unroll
    for (int i = 0; i < 5; i++) op[i] = make_float2(h[2 * i], h[2 * i + 1]);
}

extern "C" void kernel_launch(void* const* d_in, const int* in_sizes, int n_in,
                              void* d_out, int out_size, void* d_ws, size_t ws_size,
                              hipStream_t stream) {
    augru_main<<<BATCH / 256, 256, 0, stream>>>(
        (const float*)d_in[0],  (const float*)d_in[1],  (const float*)d_in[2],
        (const float*)d_in[3],  (const float*)d_in[4],  (const float*)d_in[5],
        (const float*)d_in[6],  (const float*)d_in[7],
        (const float*)d_in[8],  (const float*)d_in[9],  (const float*)d_in[10],
        (const float*)d_in[11], (const float*)d_in[12],
        (const float*)d_in[13], (const float*)d_in[14], (const float*)d_in[15],
        (const float*)d_in[16], (const float*)d_in[17],
        (float*)d_out);
}

// Round 4
// 483.810 us; speedup vs baseline: 3.5215x; 3.1949x over previous
//
#include <hip/hip_runtime.h>

#define EDIM 10
#define TDIM 50
#define BATCH 65536

// Wf layout (floats), in EXACT per-iteration consumption order so each region's
// ds_reads use small immediate offsets off a single laundered base:
//   [0..11]    bias_r (10 + 2 pad)        f4[0..2]
//   [12..23]   bias_z                     f4[3..5]
//   [24..123]  A_r = Wi_r@Ws_r            f4[6..30]
//   [124..223] A_z = Wi_z@Ws_z            f4[31..55]
//   [224..323] B_r = Wh_r@Ws_r            f4[56..80]
//   [324..423] B_z = Wh_z@Ws_z            f4[81..105]
//   [424..435] bias_h                     f4[106..108]
//   [436..535] A_h = Wi_h@Wt_h            f4[109..133]
//   [536..635] B_h = Wh_h@Wt_h            f4[134..158]
#define WTOT 640

__device__ __forceinline__ float fast_sigmoid(float x) {
    float e = __expf(-x);
    return __builtin_amdgcn_rcpf(1.0f + e);
}
__device__ __forceinline__ float fast_tanh(float x) {
    float e = __expf(2.0f * x);
    return 1.0f - 2.0f * __builtin_amdgcn_rcpf(e + 1.0f);
}

// u[e] += s[k] * M[k*10+e]; M = 25 contiguous float4s at Wb. Indices all
// compile-time after unroll.
__device__ __forceinline__ void mat_acc(const float4* Wb, const float* s, float* u) {
    #pragma unroll
    for (int c = 0; c < 25; c++) {
        float4 wv = Wb[c];
        u[(4 * c + 0) % 10] = fmaf(s[(4 * c + 0) / 10], wv.x, u[(4 * c + 0) % 10]);
        u[(4 * c + 1) % 10] = fmaf(s[(4 * c + 1) / 10], wv.y, u[(4 * c + 1) % 10]);
        u[(4 * c + 2) % 10] = fmaf(s[(4 * c + 2) / 10], wv.z, u[(4 * c + 2) % 10]);
        u[(4 * c + 3) % 10] = fmaf(s[(4 * c + 3) / 10], wv.w, u[(4 * c + 3) % 10]);
    }
}

__device__ __forceinline__ void bias_init(const float4* Wb, float* u) {
    float4 b0 = Wb[0], b1 = Wb[1], b2 = Wb[2];
    u[0] = b0.x; u[1] = b0.y; u[2] = b0.z; u[3] = b0.w;
    u[4] = b1.x; u[5] = b1.y; u[6] = b1.z; u[7] = b1.w;
    u[8] = b2.x; u[9] = b2.y;
}

// Region fence: launder the LDS byte-offset through a volatile asm. Volatile
// asms stay mutually ordered and each region's ds_reads depend on their own
// laundered offset, so the scheduler cannot bunch all 150 ds_read_b128s of an
// iteration (that bunching -> ~600 live floats -> the 2.5 GB/iter scratch
// spill seen in rounds 1-3). One region (<=25 loads + 100 fmas) stays live at
// a time: peak pressure ~220 VGPRs, spill-free, with enough in-region ILP to
// hide ds_read latency at our fixed 1 wave/SIMD occupancy.
#define FENCE() asm volatile("" : "+v"(off))
#define WP() ((const float4*)((const char*)Wf + off))

__global__ __launch_bounds__(256, 1) void augru_main(
    const float* __restrict__ x_all, const float* __restrict__ a_all,
    const float* __restrict__ h0,
    const float* __restrict__ Wi_r, const float* __restrict__ bi_r,
    const float* __restrict__ Wh_r, const float* __restrict__ Ws_r, const float* __restrict__ bs_r,
    const float* __restrict__ Wi_z, const float* __restrict__ bi_z,
    const float* __restrict__ Wh_z, const float* __restrict__ Ws_z, const float* __restrict__ bs_z,
    const float* __restrict__ Wi_h, const float* __restrict__ bi_h,
    const float* __restrict__ Wh_h, const float* __restrict__ Wt_h, const float* __restrict__ bt_h,
    float* __restrict__ out)
{
    __shared__ __align__(16) float Wf[WTOT];   // 2.56 KB collapsed weights

    // ---- preamble: collapse (Wi@Ws, Wh@Ws, bi@Ws+bs) per gate into LDS ----
    for (int s = threadIdx.x; s < WTOT; s += 256) {
        int g, kind, idx;   // kind: 0=bias, 1=A (input), 2=B (hidden)
        if      (s <  12) { g = 0; kind = 0; idx = s;       }
        else if (s <  24) { g = 1; kind = 0; idx = s - 12;  }
        else if (s < 124) { g = 0; kind = 1; idx = s - 24;  }
        else if (s < 224) { g = 1; kind = 1; idx = s - 124; }
        else if (s < 324) { g = 0; kind = 2; idx = s - 224; }
        else if (s < 424) { g = 1; kind = 2; idx = s - 324; }
        else if (s < 436) { g = 2; kind = 0; idx = s - 424; }
        else if (s < 536) { g = 2; kind = 1; idx = s - 436; }
        else              { g = 2; kind = 2; idx = s - 536; }
        const float* Wi = (g == 0) ? Wi_r : (g == 1) ? Wi_z : Wi_h;
        const float* Wh = (g == 0) ? Wh_r : (g == 1) ? Wh_z : Wh_h;
        const float* Ws = (g == 0) ? Ws_r : (g == 1) ? Ws_z : Wt_h;
        const float* bi = (g == 0) ? bi_r : (g == 1) ? bi_z : bi_h;
        const float* bs = (g == 0) ? bs_r : (g == 1) ? bs_z : bt_h;
        float v = 0.0f;
        if (kind == 0) {
            if (idx < 10) {
                v = bs[idx];
                #pragma unroll
                for (int j = 0; j < 10; j++) v += bi[j] * Ws[j * 10 + idx];
            }
        } else {
            int k = idx / 10, e = idx % 10;
            const float* M = (kind == 1) ? Wi : Wh;
            #pragma unroll
            for (int j = 0; j < 10; j++) v += M[k * 10 + j] * Ws[j * 10 + e];
        }
        Wf[s] = v;
    }
    __syncthreads();

    const int b = blockIdx.x * 256 + threadIdx.x;
    const float2* xp = (const float2*)x_all + (size_t)b * (TDIM * EDIM / 2);
    const float2* ap = (const float2*)a_all + (size_t)b * (TDIM * EDIM / 2);

    float h[EDIM];
    #pragma unroll
    for (int e = 0; e < EDIM; e++) h[e] = h0[e];

    float2 xc[5], ac[5];
    #pragma unroll
    for (int i = 0; i < 5; i++) { xc[i] = xp[i]; ac[i] = ap[i]; }

    int off = 0;   // laundered LDS byte offset (always 0; compiler can't know)
    #pragma unroll 1
    for (int t = 0; t < TDIM; t++) {
        // branchless 1-step-lookahead prefetch (clamped; keeps body branch-free
        // so the whole iteration is one scheduling region chain)
        int tn = (t < TDIM - 1) ? (t + 1) : (TDIM - 1);
        float2 xn[5], an[5];
        #pragma unroll
        for (int i = 0; i < 5; i++) {
            xn[i] = xp[tn * 5 + i];
            an[i] = ap[tn * 5 + i];
        }

        float x[EDIM], a[EDIM];
        #pragma unroll
        for (int i = 0; i < 5; i++) {
            x[2 * i] = xc[i].x; x[2 * i + 1] = xc[i].y;
            a[2 * i] = ac[i].x; a[2 * i + 1] = ac[i].y;
        }

        float ur[EDIM], uz[EDIM];
        FENCE(); { const float4* P = WP(); bias_init(P + 0, ur); bias_init(P + 3, uz); }
        FENCE(); { const float4* P = WP(); mat_acc(P + 6,   x, ur); }   // A_r
        FENCE(); { const float4* P = WP(); mat_acc(P + 31,  x, uz); }   // A_z
        FENCE(); { const float4* P = WP(); mat_acc(P + 56,  h, ur); }   // B_r
        FENCE(); { const float4* P = WP(); mat_acc(P + 81,  h, uz); }   // B_z

        float r[EDIM], z[EDIM], hz[EDIM];
        #pragma unroll
        for (int e = 0; e < EDIM; e++) {
            r[e] = fast_sigmoid(ur[e]);
            z[e] = fast_sigmoid(uz[e]);
            hz[e] = h[e] * z[e];
        }

        float uh[EDIM];
        FENCE(); { const float4* P = WP(); bias_init(P + 106, uh); mat_acc(P + 109, x, uh); }  // c_h + A_h
        FENCE(); { const float4* P = WP(); mat_acc(P + 134, hz, uh); }  // B_h

        #pragma unroll
        for (int e = 0; e < EDIM; e++) {
            float hc = fast_tanh(uh[e]);
            float Ra = a[e] * r[e];
            h[e] = h[e] + Ra * (hc - h[e]);
        }

        #pragma unroll
        for (int i = 0; i < 5; i++) { xc[i] = xn[i]; ac[i] = an[i]; }
    }

    float2* op = (float2*)out + (size_t)b * (EDIM / 2);
    #pragma unroll
    for (int i = 0; i < 5; i++) op[i] = make_float2(h[2 * i], h[2 * i + 1]);
}

extern "C" void kernel_launch(void* const* d_in, const int* in_sizes, int n_in,
                              void* d_out, int out_size, void* d_ws, size_t ws_size,
                              hipStream_t stream) {
    augru_main<<<BATCH / 256, 256, 0, stream>>>(
        (const float*)d_in[0],  (const float*)d_in[1],  (const float*)d_in[2],
        (const float*)d_in[3],  (const float*)d_in[4],  (const float*)d_in[5],
        (const float*)d_in[6],  (const float*)d_in[7],
        (const float*)d_in[8],  (const float*)d_in[9],  (const float*)d_in[10],
        (const float*)d_in[11], (const float*)d_in[12],
        (const float*)d_in[13], (const float*)d_in[14], (const float*)d_in[15],
        (const float*)d_in[16], (const float*)d_in[17],
        (float*)d_out);
}

// Round 5
// 446.933 us; speedup vs baseline: 3.8120x; 1.0825x over previous
//
#include <hip/hip_runtime.h>

#define EDIM 10
#define TDIM 50
#define BATCH 65536

// Collapsed-weight layout (floats 0..639) — exactly 10 VGPRs x 64 lanes:
//   [0..11]    bias_r (10 + 2 pad)
//   [12..23]   bias_z
//   [24..123]  A_r = Wi_r@Ws_r   (indexed [k*10+e])
//   [124..223] A_z = Wi_z@Ws_z
//   [224..323] B_r = Wh_r@Ws_r
//   [324..423] B_z = Wh_z@Ws_z
//   [424..435] bias_h
//   [436..535] A_h = Wi_h@Wt_h
//   [536..635] B_h = Wh_h@Wt_h   (636..639 pad)
#define WTOT 640

__device__ __forceinline__ float fast_sigmoid(float x) {
    float e = __expf(-x);
    return __builtin_amdgcn_rcpf(1.0f + e);
}
__device__ __forceinline__ float fast_tanh(float x) {
    float e = __expf(2.0f * x);
    return 1.0f - 2.0f * __builtin_amdgcn_rcpf(e + 1.0f);
}

// Weight-operand path (round-5 change): weights live lane-distributed in 10
// VGPRs (wreg[j] = Wf[j*64 + lane]); each use is v_readlane -> SGPR, consumed
// as the free scalar operand of v_fma. This moves weight fetch off the
// CU-shared DS pipe (the round-4 bottleneck: 636 ds_read_b128/CU/iter ~ 7.6k
// cyc) onto each wave's private SIMD (~2 cyc/readlane), with zero LDS traffic
// in the t-loop.
#define RL(i) __uint_as_float(__builtin_amdgcn_readlane( \
                  __float_as_uint(wreg[(i) >> 6]), (i) & 63))

// Per-region laundering of the 10 weight VGPRs: readlanes in each region
// depend on the region's laundered defs, so LICM cannot hoist the 600
// loop-invariant readlanes (no SGPR budget for them -> would spill).
#define FENCEW() asm volatile("" : "+v"(wreg[0]), "+v"(wreg[1]), "+v"(wreg[2]), \
    "+v"(wreg[3]), "+v"(wreg[4]), "+v"(wreg[5]), "+v"(wreg[6]), "+v"(wreg[7]), \
    "+v"(wreg[8]), "+v"(wreg[9]))

__global__ __launch_bounds__(256, 1) void augru_main(
    const float* __restrict__ x_all, const float* __restrict__ a_all,
    const float* __restrict__ h0,
    const float* __restrict__ Wi_r, const float* __restrict__ bi_r,
    const float* __restrict__ Wh_r, const float* __restrict__ Ws_r, const float* __restrict__ bs_r,
    const float* __restrict__ Wi_z, const float* __restrict__ bi_z,
    const float* __restrict__ Wh_z, const float* __restrict__ Ws_z, const float* __restrict__ bs_z,
    const float* __restrict__ Wi_h, const float* __restrict__ bi_h,
    const float* __restrict__ Wh_h, const float* __restrict__ Wt_h, const float* __restrict__ bt_h,
    float* __restrict__ out)
{
    __shared__ __align__(16) float Wf[WTOT];   // 2.56 KB collapsed weights

    // ---- preamble: collapse (Wi@Ws, Wh@Ws, bi@Ws+bs) per gate into LDS ----
    for (int s = threadIdx.x; s < WTOT; s += 256) {
        int g, kind, idx;   // kind: 0=bias, 1=A (input), 2=B (hidden)
        if      (s <  12) { g = 0; kind = 0; idx = s;       }
        else if (s <  24) { g = 1; kind = 0; idx = s - 12;  }
        else if (s < 124) { g = 0; kind = 1; idx = s - 24;  }
        else if (s < 224) { g = 1; kind = 1; idx = s - 124; }
        else if (s < 324) { g = 0; kind = 2; idx = s - 224; }
        else if (s < 424) { g = 1; kind = 2; idx = s - 324; }
        else if (s < 436) { g = 2; kind = 0; idx = s - 424; }
        else if (s < 536) { g = 2; kind = 1; idx = s - 436; }
        else              { g = 2; kind = 2; idx = s - 536; }
        const float* Wi = (g == 0) ? Wi_r : (g == 1) ? Wi_z : Wi_h;
        const float* Wh = (g == 0) ? Wh_r : (g == 1) ? Wh_z : Wh_h;
        const float* Ws = (g == 0) ? Ws_r : (g == 1) ? Ws_z : Wt_h;
        const float* bi = (g == 0) ? bi_r : (g == 1) ? bi_z : bi_h;
        const float* bs = (g == 0) ? bs_r : (g == 1) ? bs_z : bt_h;
        float v = 0.0f;
        if (kind == 0) {
            if (idx < 10) {
                v = bs[idx];
                #pragma unroll
                for (int j = 0; j < 10; j++) v += bi[j] * Ws[j * 10 + idx];
            }
        } else if (idx < 100) {
            int k = idx / 10, e = idx % 10;
            const float* M = (kind == 1) ? Wi : Wh;
            #pragma unroll
            for (int j = 0; j < 10; j++) v += M[k * 10 + j] * Ws[j * 10 + e];
        }
        Wf[s] = v;
    }
    __syncthreads();

    // lane-distributed weight registers: wreg[j] = Wf[j*64 + lane]
    const int lane = threadIdx.x & 63;
    float wreg[10];
    #pragma unroll
    for (int j = 0; j < 10; j++) wreg[j] = Wf[j * 64 + lane];

    const int b = blockIdx.x * 256 + threadIdx.x;
    const float2* xp = (const float2*)x_all + (size_t)b * (TDIM * EDIM / 2);
    const float2* ap = (const float2*)a_all + (size_t)b * (TDIM * EDIM / 2);

    float h[EDIM];
    #pragma unroll
    for (int e = 0; e < EDIM; e++) h[e] = h0[e];

    float2 xc[5], ac[5];
    #pragma unroll
    for (int i = 0; i < 5; i++) { xc[i] = xp[i]; ac[i] = ap[i]; }

    #pragma unroll 1
    for (int t = 0; t < TDIM; t++) {
        // branchless 1-step-lookahead prefetch (clamped)
        int tn = (t < TDIM - 1) ? (t + 1) : (TDIM - 1);
        float2 xn[5], an[5];
        #pragma unroll
        for (int i = 0; i < 5; i++) {
            xn[i] = xp[tn * 5 + i];
            an[i] = ap[tn * 5 + i];
        }

        float x[EDIM], a[EDIM];
        #pragma unroll
        for (int i = 0; i < 5; i++) {
            x[2 * i] = xc[i].x; x[2 * i + 1] = xc[i].y;
            a[2 * i] = ac[i].x; a[2 * i + 1] = ac[i].y;
        }

        float ur[EDIM], uz[EDIM];
        FENCEW();
        #pragma unroll
        for (int e = 0; e < EDIM; e++) { ur[e] = RL(0 + e); uz[e] = RL(12 + e); }
        FENCEW();
        #pragma unroll
        for (int k = 0; k < EDIM; k++)       // A_r: ur += x @ A_r
            #pragma unroll
            for (int e = 0; e < EDIM; e++) ur[e] = fmaf(x[k], RL(24 + k * 10 + e), ur[e]);
        FENCEW();
        #pragma unroll
        for (int k = 0; k < EDIM; k++)       // A_z
            #pragma unroll
            for (int e = 0; e < EDIM; e++) uz[e] = fmaf(x[k], RL(124 + k * 10 + e), uz[e]);
        FENCEW();
        #pragma unroll
        for (int k = 0; k < EDIM; k++)       // B_r: ur += h @ B_r
            #pragma unroll
            for (int e = 0; e < EDIM; e++) ur[e] = fmaf(h[k], RL(224 + k * 10 + e), ur[e]);
        FENCEW();
        #pragma unroll
        for (int k = 0; k < EDIM; k++)       // B_z
            #pragma unroll
            for (int e = 0; e < EDIM; e++) uz[e] = fmaf(h[k], RL(324 + k * 10 + e), uz[e]);

        float r[EDIM], z[EDIM], hz[EDIM];
        #pragma unroll
        for (int e = 0; e < EDIM; e++) {
            r[e] = fast_sigmoid(ur[e]);
            z[e] = fast_sigmoid(uz[e]);
            hz[e] = h[e] * z[e];
        }

        float uh[EDIM];
        FENCEW();
        #pragma unroll
        for (int e = 0; e < EDIM; e++) uh[e] = RL(424 + e);
        #pragma unroll
        for (int k = 0; k < EDIM; k++)       // A_h: uh += x @ A_h
            #pragma unroll
            for (int e = 0; e < EDIM; e++) uh[e] = fmaf(x[k], RL(436 + k * 10 + e), uh[e]);
        FENCEW();
        #pragma unroll
        for (int k = 0; k < EDIM; k++)       // B_h: uh += (h*z) @ B_h
            #pragma unroll
            for (int e = 0; e < EDIM; e++) uh[e] = fmaf(hz[k], RL(536 + k * 10 + e), uh[e]);

        #pragma unroll
        for (int e = 0; e < EDIM; e++) {
            float hc = fast_tanh(uh[e]);
            float Ra = a[e] * r[e];
            h[e] = h[e] + Ra * (hc - h[e]);
        }

        #pragma unroll
        for (int i = 0; i < 5; i++) { xc[i] = xn[i]; ac[i] = an[i]; }
    }

    float2* op = (float2*)out + (size_t)b * (EDIM / 2);
    #pragma unroll
    for (int i = 0; i < 5; i++) op[i] = make_float2(h[2 * i], h[2 * i + 1]);
}

extern "C" void kernel_launch(void* const* d_in, const int* in_sizes, int n_in,
                              void* d_out, int out_size, void* d_ws, size_t ws_size,
                              hipStream_t stream) {
    augru_main<<<BATCH / 256, 256, 0, stream>>>(
        (const float*)d_in[0],  (const float*)d_in[1],  (const float*)d_in[2],
        (const float*)d_in[3],  (const float*)d_in[4],  (const float*)d_in[5],
        (const float*)d_in[6],  (const float*)d_in[7],
        (const float*)d_in[8],  (const float*)d_in[9],  (const float*)d_in[10],
        (const float*)d_in[11], (const float*)d_in[12],
        (const float*)d_in[13], (const float*)d_in[14], (const float*)d_in[15],
        (const float*)d_in[16], (const float*)d_in[17],
        (float*)d_out);
}

// Round 6
// 396.877 us; speedup vs baseline: 4.2929x; 1.1261x over previous
//
#include <hip/hip_runtime.h>

#define EDIM 10
#define TDIM 50
#define BATCH 65536
#define RPB   128   // rows per block (block = 4 waves: 2 waves per column-half)
#define LSTR  11    // LDS exchange row stride: 11 coprime 32 -> 2-way banks = free

// Collapsed-weight layout (floats 0..639) — exactly 10 VGPRs x 64 lanes:
//   [0..11]    bias_r (10 + 2 pad)
//   [12..23]   bias_z
//   [24..123]  A_r = Wi_r@Ws_r   (indexed [k*10+e])
//   [124..223] A_z = Wi_z@Ws_z
//   [224..323] B_r = Wh_r@Ws_r
//   [324..423] B_z = Wh_z@Ws_z
//   [424..435] bias_h
//   [436..535] A_h = Wi_h@Wt_h
//   [536..635] B_h = Wh_h@Wt_h   (636..639 pad)
#define WTOT 640

__device__ __forceinline__ float fast_sigmoid(float x) {
    float e = __expf(-x);
    return __builtin_amdgcn_rcpf(1.0f + e);
}
__device__ __forceinline__ float fast_tanh(float x) {
    float e = __expf(2.0f * x);
    return 1.0f - 2.0f * __builtin_amdgcn_rcpf(e + 1.0f);
}

// Weights lane-distributed in 10 VGPRs; each use = v_readlane (wave-uniform,
// compile-time lane select) feeding the free scalar operand of v_fma.
#define RL(i) __uint_as_float(__builtin_amdgcn_readlane( \
                  __float_as_uint(wreg[(i) >> 6]), (i) & 63))
// Per-region laundering: blocks LICM from hoisting loop-invariant readlanes
// (no SGPR budget for 600 of them -> would spill). Proven in rounds 4-5.
#define FENCEW() asm volatile("" : "+v"(wreg[0]), "+v"(wreg[1]), "+v"(wreg[2]), \
    "+v"(wreg[3]), "+v"(wreg[4]), "+v"(wreg[5]), "+v"(wreg[6]), "+v"(wreg[7]), \
    "+v"(wreg[8]), "+v"(wreg[9]))

// Load this half's 5 attention values a[E0..E0+4] from row base p (+t*10 applied
// by caller). Row base is 8B-aligned (40*row + 40*t bytes), so the float2s below
// are aligned in both halves.
template<int E0>
__device__ __forceinline__ void load_a(const float* __restrict__ p, float* a) {
    if constexpr (E0 == 0) {
        float2 v0 = *(const float2*)(p + 0);
        float2 v1 = *(const float2*)(p + 2);
        a[0] = v0.x; a[1] = v0.y; a[2] = v1.x; a[3] = v1.y; a[4] = p[4];
    } else {
        a[0] = p[5];
        float2 v0 = *(const float2*)(p + 6);
        float2 v1 = *(const float2*)(p + 8);
        a[1] = v0.x; a[2] = v0.y; a[3] = v1.x; a[4] = v1.y;
    }
}

// One column-half of the recurrence: this thread owns columns E0..E0+4 of its
// row. Partner half (P0) exchanged via LDS: hz mid-iter (B1), h end-iter (B2).
// Both halves execute identical instruction cadences -> barriers wave-matched.
template<int E0>
__device__ __forceinline__ void augru_half(
    const float2* __restrict__ xp,   // row x base (float2 units)
    const float*  __restrict__ ar,   // row a base (float units)
    const float*  __restrict__ h0,
    float* wreg,
    float* __restrict__ hbuf, float* __restrict__ hzbuf,
    int row_l, float* __restrict__ orow)
{
    constexpr int P0 = 5 - E0;

    float h[5];
    #pragma unroll
    for (int j = 0; j < 5; j++) h[j] = h0[E0 + j];
    #pragma unroll
    for (int j = 0; j < 5; j++) hbuf[row_l * LSTR + E0 + j] = h[j];
    __syncthreads();   // h-init visible to partner before iter 0

    float2 xc[5]; float ac[5];
    #pragma unroll
    for (int i = 0; i < 5; i++) xc[i] = xp[i];
    load_a<E0>(ar, ac);

    #pragma unroll 1
    for (int t = 0; t < TDIM; t++) {
        // partner h from previous iter (safe: written pre-B2, read post-B2)
        float hf[10];
        #pragma unroll
        for (int j = 0; j < 5; j++) {
            hf[E0 + j] = h[j];
            hf[P0 + j] = hbuf[row_l * LSTR + P0 + j];
        }

        // branchless 1-step-lookahead prefetch (clamped)
        int tn = (t < TDIM - 1) ? (t + 1) : t;
        float2 xn[5]; float an[5];
        #pragma unroll
        for (int i = 0; i < 5; i++) xn[i] = xp[tn * 5 + i];
        load_a<E0>(ar + tn * 10, an);

        float x[10];
        #pragma unroll
        for (int i = 0; i < 5; i++) { x[2 * i] = xc[i].x; x[2 * i + 1] = xc[i].y; }

        float ur[5], uz[5];
        FENCEW();
        #pragma unroll
        for (int j = 0; j < 5; j++) { ur[j] = RL(0 + E0 + j); uz[j] = RL(12 + E0 + j); }
        FENCEW();
        #pragma unroll
        for (int k = 0; k < 10; k++)    // x @ A_r
            #pragma unroll
            for (int j = 0; j < 5; j++) ur[j] = fmaf(x[k], RL(24 + k * 10 + E0 + j), ur[j]);
        FENCEW();
        #pragma unroll
        for (int k = 0; k < 10; k++)    // x @ A_z
            #pragma unroll
            for (int j = 0; j < 5; j++) uz[j] = fmaf(x[k], RL(124 + k * 10 + E0 + j), uz[j]);
        FENCEW();
        #pragma unroll
        for (int k = 0; k < 10; k++)    // h @ B_r
            #pragma unroll
            for (int j = 0; j < 5; j++) ur[j] = fmaf(hf[k], RL(224 + k * 10 + E0 + j), ur[j]);
        FENCEW();
        #pragma unroll
        for (int k = 0; k < 10; k++)    // h @ B_z
            #pragma unroll
            for (int j = 0; j < 5; j++) uz[j] = fmaf(hf[k], RL(324 + k * 10 + E0 + j), uz[j]);

        float z[5], hzo[5];
        #pragma unroll
        for (int j = 0; j < 5; j++) {
            z[j] = fast_sigmoid(uz[j]);
            hzo[j] = h[j] * z[j];
        }
        #pragma unroll
        for (int j = 0; j < 5; j++) hzbuf[row_l * LSTR + E0 + j] = hzo[j];
        __syncthreads();   // B1: hz halves exchanged

        float hzf[10];
        #pragma unroll
        for (int j = 0; j < 5; j++) {
            hzf[E0 + j] = hzo[j];
            hzf[P0 + j] = hzbuf[row_l * LSTR + P0 + j];
        }

        float uh[5];
        FENCEW();
        #pragma unroll
        for (int j = 0; j < 5; j++) uh[j] = RL(424 + E0 + j);
        #pragma unroll
        for (int k = 0; k < 10; k++)    // x @ A_h
            #pragma unroll
            for (int j = 0; j < 5; j++) uh[j] = fmaf(x[k], RL(436 + k * 10 + E0 + j), uh[j]);
        FENCEW();
        #pragma unroll
        for (int k = 0; k < 10; k++)    // (h*z) @ B_h
            #pragma unroll
            for (int j = 0; j < 5; j++) uh[j] = fmaf(hzf[k], RL(536 + k * 10 + E0 + j), uh[j]);

        #pragma unroll
        for (int j = 0; j < 5; j++) {
            float r  = fast_sigmoid(ur[j]);
            float hc = fast_tanh(uh[j]);
            float Ra = ac[j] * r;
            h[j] = h[j] + Ra * (hc - h[j]);
        }

        #pragma unroll
        for (int j = 0; j < 5; j++) hbuf[row_l * LSTR + E0 + j] = h[j];
        __syncthreads();   // B2: h halves exchanged

        #pragma unroll
        for (int i = 0; i < 5; i++) xc[i] = xn[i];
        #pragma unroll
        for (int j = 0; j < 5; j++) ac[j] = an[j];
    }

    // store own half (row base 40B-aligned -> these float2s are 8B-aligned)
    if constexpr (E0 == 0) {
        *(float2*)(orow + 0) = make_float2(h[0], h[1]);
        *(float2*)(orow + 2) = make_float2(h[2], h[3]);
        orow[4] = h[4];
    } else {
        orow[5] = h[0];
        *(float2*)(orow + 6) = make_float2(h[1], h[2]);
        *(float2*)(orow + 8) = make_float2(h[3], h[4]);
    }
}

__global__ __launch_bounds__(256, 2) void augru_main(
    const float* __restrict__ x_all, const float* __restrict__ a_all,
    const float* __restrict__ h0,
    const float* __restrict__ Wi_r, const float* __restrict__ bi_r,
    const float* __restrict__ Wh_r, const float* __restrict__ Ws_r, const float* __restrict__ bs_r,
    const float* __restrict__ Wi_z, const float* __restrict__ bi_z,
    const float* __restrict__ Wh_z, const float* __restrict__ Ws_z, const float* __restrict__ bs_z,
    const float* __restrict__ Wi_h, const float* __restrict__ bi_h,
    const float* __restrict__ Wh_h, const float* __restrict__ Wt_h, const float* __restrict__ bt_h,
    float* __restrict__ out)
{
    __shared__ __align__(16) float Wf[WTOT];           // 2.56 KB collapsed weights
    __shared__ float hbuf[RPB * LSTR];                 // h exchange (5.6 KB)
    __shared__ float hzbuf[RPB * LSTR];                // hz exchange (5.6 KB)

    // ---- preamble: collapse (Wi@Ws, Wh@Ws, bi@Ws+bs) per gate into LDS ----
    for (int s = threadIdx.x; s < WTOT; s += 256) {
        int g, kind, idx;   // kind: 0=bias, 1=A (input), 2=B (hidden)
        if      (s <  12) { g = 0; kind = 0; idx = s;       }
        else if (s <  24) { g = 1; kind = 0; idx = s - 12;  }
        else if (s < 124) { g = 0; kind = 1; idx = s - 24;  }
        else if (s < 224) { g = 1; kind = 1; idx = s - 124; }
        else if (s < 324) { g = 0; kind = 2; idx = s - 224; }
        else if (s < 424) { g = 1; kind = 2; idx = s - 324; }
        else if (s < 436) { g = 2; kind = 0; idx = s - 424; }
        else if (s < 536) { g = 2; kind = 1; idx = s - 436; }
        else              { g = 2; kind = 2; idx = s - 536; }
        const float* Wi = (g == 0) ? Wi_r : (g == 1) ? Wi_z : Wi_h;
        const float* Wh = (g == 0) ? Wh_r : (g == 1) ? Wh_z : Wh_h;
        const float* Ws = (g == 0) ? Ws_r : (g == 1) ? Ws_z : Wt_h;
        const float* bi = (g == 0) ? bi_r : (g == 1) ? bi_z : bi_h;
        const float* bs = (g == 0) ? bs_r : (g == 1) ? bs_z : bt_h;
        float v = 0.0f;
        if (kind == 0) {
            if (idx < 10) {
                v = bs[idx];
                #pragma unroll
                for (int j = 0; j < 10; j++) v += bi[j] * Ws[j * 10 + idx];
            }
        } else if (idx < 100) {
            int k = idx / 10, e = idx % 10;
            const float* M = (kind == 1) ? Wi : Wh;
            #pragma unroll
            for (int j = 0; j < 10; j++) v += M[k * 10 + j] * Ws[j * 10 + e];
        }
        Wf[s] = v;
    }
    __syncthreads();

    // lane-distributed weight registers: wreg[j] = Wf[j*64 + lane]
    const int lane = threadIdx.x & 63;
    float wreg[10];
    #pragma unroll
    for (int j = 0; j < 10; j++) wreg[j] = Wf[j * 64 + lane];

    // wave-pair split: tid[0..127] -> columns 0..4, tid[128..255] -> 5..9,
    // both groups covering the same 128 rows. Condition made explicitly
    // wave-uniform (SGPR) -> pure scalar branch, no exec masking.
    const int row_l = threadIdx.x & (RPB - 1);
    const int half  = __builtin_amdgcn_readfirstlane(threadIdx.x >> 7);
    const int row   = blockIdx.x * RPB + row_l;

    const float2* xp = (const float2*)x_all + (size_t)row * (TDIM * EDIM / 2);
    const float*  ar = a_all + (size_t)row * (TDIM * EDIM);
    float* orow = out + (size_t)row * EDIM;

    if (half == 0)
        augru_half<0>(xp, ar, h0, wreg, hbuf, hzbuf, row_l, orow);
    else
        augru_half<5>(xp, ar, h0, wreg, hbuf, hzbuf, row_l, orow);
}

extern "C" void kernel_launch(void* const* d_in, const int* in_sizes, int n_in,
                              void* d_out, int out_size, void* d_ws, size_t ws_size,
                              hipStream_t stream) {
    augru_main<<<BATCH / RPB, 256, 0, stream>>>(
        (const float*)d_in[0],  (const float*)d_in[1],  (const float*)d_in[2],
        (const float*)d_in[3],  (const float*)d_in[4],  (const float*)d_in[5],
        (const float*)d_in[6],  (const float*)d_in[7],
        (const float*)d_in[8],  (const float*)d_in[9],  (const float*)d_in[10],
        (const float*)d_in[11], (const float*)d_in[12],
        (const float*)d_in[13], (const float*)d_in[14], (const float*)d_in[15],
        (const float*)d_in[16], (const float*)d_in[17],
        (float*)d_out);
}